// Round 1
// baseline (477.309 us; speedup 1.0000x reference)
//
#include <hip/hip_runtime.h>
#include <stdint.h>

// GCN: z = A_hat( relu( A_hat(x@W1) + b1 ) @ W2 ) + b2, A_hat = D^-1/2 (A+I) D^-1/2
// Strategy: build CSR by dst once per call (ws is re-poisoned), dense f32 GEMMs
// with LDS tiling, one-wave-per-node register aggregation (no fp32 atomics).

__device__ __forceinline__ int wave_incl_scan(int v, int lane) {
#pragma unroll
  for (int d = 1; d < 64; d <<= 1) {
    int o = __shfl_up(v, d);
    if (lane >= d) v += o;
  }
  return v;
}

__global__ __launch_bounds__(256) void hist_kernel(const int* __restrict__ dst, int E,
                                                   int* __restrict__ counts) {
  int i = blockIdx.x * 256 + threadIdx.x;
  if (i < E) atomicAdd(&counts[dst[i]], 1);
}

__global__ __launch_bounds__(256) void bsum_kernel(const int* __restrict__ counts,
                                                   int* __restrict__ bsum, int n) {
  int i = blockIdx.x * 256 + threadIdx.x;
  int c = (i < n) ? counts[i] : 0;
#pragma unroll
  for (int d = 32; d > 0; d >>= 1) c += __shfl_down(c, d);
  __shared__ int ws[4];
  if ((threadIdx.x & 63) == 0) ws[threadIdx.x >> 6] = c;
  __syncthreads();
  if (threadIdx.x == 0) bsum[blockIdx.x] = ws[0] + ws[1] + ws[2] + ws[3];
}

// single block; requires nb <= 256 (nb = ceil(50000/256) = 196)
__global__ __launch_bounds__(256) void scan_bsums_kernel(const int* __restrict__ bsum,
                                                         int* __restrict__ boff, int nb) {
  int t = threadIdx.x, lane = t & 63;
  int v = (t < nb) ? bsum[t] : 0;
  int incl = wave_incl_scan(v, lane);
  __shared__ int wsum[4];
  if (lane == 63) wsum[t >> 6] = incl;
  __syncthreads();
  int pre = 0;
  for (int j = 0; j < (t >> 6); ++j) pre += wsum[j];
  if (t < nb) boff[t] = pre + incl - v;
}

__global__ __launch_bounds__(256) void scan_apply_kernel(const int* __restrict__ counts,
                                                         const int* __restrict__ boff,
                                                         int* __restrict__ offsets,
                                                         int* __restrict__ cursor,
                                                         float* __restrict__ dinv, int n) {
  int b = blockIdx.x, t = threadIdx.x, lane = t & 63;
  int i = b * 256 + t;
  int c = (i < n) ? counts[i] : 0;
  int incl = wave_incl_scan(c, lane);
  __shared__ int wsum[4];
  if (lane == 63) wsum[t >> 6] = incl;
  __syncthreads();
  int pre = 0;
  for (int j = 0; j < (t >> 6); ++j) pre += wsum[j];
  int excl = boff[b] + pre + incl - c;
  if (i < n) {
    offsets[i] = excl;
    cursor[i] = excl;
    dinv[i] = rsqrtf((float)(c + 1));  // +1 self-loop; deg >= 1 always
    if (i == n - 1) offsets[n] = excl + c;
  }
}

__global__ __launch_bounds__(256) void fill_kernel(const int* __restrict__ src,
                                                   const int* __restrict__ dst, int E,
                                                   int* __restrict__ cursor,
                                                   int* __restrict__ csr) {
  int i = blockIdx.x * 256 + threadIdx.x;
  if (i < E) {
    int d = dst[i];
    int pos = atomicAdd(&cursor[d], 1);
    csr[pos] = src[i];
  }
}

// out[n][64] = A[n][K] @ W[K][64]; K % 32 == 0. 128-row tile, thread = 8 rows x 4 cols.
__global__ __launch_bounds__(256) void gemm64_kernel(const float* __restrict__ A,
                                                     const float* __restrict__ W,
                                                     float* __restrict__ out, int n, int K) {
  __shared__ float xs[128][36];   // pad 36: row stride 144 B -> float4-aligned reads
  __shared__ float wsm[32][64];
  const int t = threadIdx.x;
  const int row0 = blockIdx.x * 128;
  const int c0 = (t & 15) * 4;
  const int r0 = (t >> 4) * 8;
  float acc[8][4] = {};
  for (int k0 = 0; k0 < K; k0 += 32) {
#pragma unroll
    for (int it = 0; it < 4; ++it) {
      int r = (t >> 3) + it * 32;
      int kk = (t & 7) * 4;
      int gr = row0 + r;
      float4 v = make_float4(0.f, 0.f, 0.f, 0.f);
      if (gr < n) v = *(const float4*)&A[(size_t)gr * K + k0 + kk];
      *(float4*)&xs[r][kk] = v;
    }
#pragma unroll
    for (int it = 0; it < 2; ++it) {
      int idx = t + it * 256;
      int kk = idx >> 4;
      int cc = (idx & 15) * 4;
      *(float4*)&wsm[kk][cc] = *(const float4*)&W[(size_t)(k0 + kk) * 64 + cc];
    }
    __syncthreads();
#pragma unroll
    for (int kk = 0; kk < 32; kk += 4) {
      float wv[4][4];
#pragma unroll
      for (int j = 0; j < 4; ++j) {
        float4 wj = *(const float4*)&wsm[kk + j][c0];
        wv[j][0] = wj.x; wv[j][1] = wj.y; wv[j][2] = wj.z; wv[j][3] = wj.w;
      }
#pragma unroll
      for (int i = 0; i < 8; ++i) {
        float4 xi = *(const float4*)&xs[r0 + i][kk];
        float xa[4] = {xi.x, xi.y, xi.z, xi.w};
#pragma unroll
        for (int j = 0; j < 4; ++j)
#pragma unroll
          for (int c = 0; c < 4; ++c)
            acc[i][c] = fmaf(xa[j], wv[j][c], acc[i][c]);
      }
    }
    __syncthreads();
  }
#pragma unroll
  for (int i = 0; i < 8; ++i) {
    int gr = row0 + r0 + i;
    if (gr < n) {
      float4 o = make_float4(acc[i][0], acc[i][1], acc[i][2], acc[i][3]);
      *(float4*)&out[(size_t)gr * 64 + c0] = o;
    }
  }
}

// one wave per node; lane = feature dim. acc += sum_in-edges H[src]*dinv[s]*dinv[v] + self.
__global__ __launch_bounds__(256) void agg_kernel(const float* __restrict__ H,
                                                  const int* __restrict__ offsets,
                                                  const int* __restrict__ csr,
                                                  const float* __restrict__ dinv,
                                                  const float* __restrict__ bias,
                                                  float* __restrict__ out, int n, int do_relu) {
  int lane = threadIdx.x & 63;
  int v = blockIdx.x * 4 + (threadIdx.x >> 6);
  if (v >= n) return;
  float dv = dinv[v];
  float acc = H[(size_t)v * 64 + lane] * (dv * dv);  // self-loop
  int e0 = offsets[v], e1 = offsets[v + 1];
  for (int e = e0; e < e1; ++e) {
    int s = csr[e];
    float w = dinv[s] * dv;
    acc = fmaf(H[(size_t)s * 64 + lane], w, acc);
  }
  float r = acc + bias[lane];
  if (do_relu) r = fmaxf(r, 0.f);
  out[(size_t)v * 64 + lane] = r;
}

extern "C" void kernel_launch(void* const* d_in, const int* in_sizes, int n_in,
                              void* d_out, int out_size, void* d_ws, size_t ws_size,
                              hipStream_t stream) {
  const float* x = (const float*)d_in[0];
  const int* ei = (const int*)d_in[1];
  const float* W1 = (const float*)d_in[2];
  const float* b1 = (const float*)d_in[3];
  const float* W2 = (const float*)d_in[4];
  const float* b2 = (const float*)d_in[5];
  float* out = (float*)d_out;

  const int HID = in_sizes[3];           // 64
  const int IN_DIM = in_sizes[2] / HID;  // 512
  const int N = in_sizes[0] / IN_DIM;    // 50000
  const int E = in_sizes[1] / 2;         // 800000
  const int NB = (N + 255) / 256;        // 196 (<=256 for single-block scan)

  uint8_t* p = (uint8_t*)d_ws;
  auto alloc = [&](size_t bytes) {
    void* r = (void*)p;
    p += (bytes + 255) & ~(size_t)255;
    return r;
  };
  int* counts = (int*)alloc((size_t)N * 4);
  int* offsets = (int*)alloc((size_t)(N + 1) * 4);
  int* cursor = (int*)alloc((size_t)N * 4);
  int* bsum = (int*)alloc((size_t)NB * 4);
  int* boff = (int*)alloc((size_t)NB * 4);
  float* dinv = (float*)alloc((size_t)N * 4);
  int* csr = (int*)alloc((size_t)E * 4);
  float* h0 = (float*)alloc((size_t)N * HID * 4);  // also reused as h1
  float* h = (float*)alloc((size_t)N * HID * 4);

  const int* srcp = ei;
  const int* dstp = ei + E;

  hipMemsetAsync(counts, 0, (size_t)N * 4, stream);
  hist_kernel<<<(E + 255) / 256, 256, 0, stream>>>(dstp, E, counts);
  bsum_kernel<<<NB, 256, 0, stream>>>(counts, bsum, N);
  scan_bsums_kernel<<<1, 256, 0, stream>>>(bsum, boff, NB);
  scan_apply_kernel<<<NB, 256, 0, stream>>>(counts, boff, offsets, cursor, dinv, N);
  fill_kernel<<<(E + 255) / 256, 256, 0, stream>>>(srcp, dstp, E, cursor, csr);

  gemm64_kernel<<<(N + 127) / 128, 256, 0, stream>>>(x, W1, h0, N, IN_DIM);
  agg_kernel<<<(N + 3) / 4, 256, 0, stream>>>(h0, offsets, csr, dinv, b1, h, N, 1);
  gemm64_kernel<<<(N + 127) / 128, 256, 0, stream>>>(h, W2, h0, N, HID);
  agg_kernel<<<(N + 3) / 4, 256, 0, stream>>>(h0, offsets, csr, dinv, b2, out, N, 0);
}

// Round 2
// 432.123 us; speedup vs baseline: 1.1046x; 1.1046x over previous
//
#include <hip/hip_runtime.h>
#include <stdint.h>

// GCN: z = A_hat( relu( A_hat(x@W1) + b1 ) @ W2 ) + b2, A_hat = D^-1/2 (A+I) D^-1/2
// R2: gemm -> 64-row tiles (782 blocks, ~3/CU uniform) + double-buffered LDS;
//     agg  -> 16 lanes/node float4, shfl-batched edge meta, unrolled-16 gather pipeline.

__device__ __forceinline__ int wave_incl_scan(int v, int lane) {
#pragma unroll
  for (int d = 1; d < 64; d <<= 1) {
    int o = __shfl_up(v, d);
    if (lane >= d) v += o;
  }
  return v;
}

__global__ __launch_bounds__(256) void hist_kernel(const int* __restrict__ dst, int E,
                                                   int* __restrict__ counts) {
  int i = blockIdx.x * 256 + threadIdx.x;
  if (i < E) atomicAdd(&counts[dst[i]], 1);
}

__global__ __launch_bounds__(256) void bsum_kernel(const int* __restrict__ counts,
                                                   int* __restrict__ bsum, int n) {
  int i = blockIdx.x * 256 + threadIdx.x;
  int c = (i < n) ? counts[i] : 0;
#pragma unroll
  for (int d = 32; d > 0; d >>= 1) c += __shfl_down(c, d);
  __shared__ int ws[4];
  if ((threadIdx.x & 63) == 0) ws[threadIdx.x >> 6] = c;
  __syncthreads();
  if (threadIdx.x == 0) bsum[blockIdx.x] = ws[0] + ws[1] + ws[2] + ws[3];
}

// single block; requires nb <= 256 (nb = ceil(50000/256) = 196)
__global__ __launch_bounds__(256) void scan_bsums_kernel(const int* __restrict__ bsum,
                                                         int* __restrict__ boff, int nb) {
  int t = threadIdx.x, lane = t & 63;
  int v = (t < nb) ? bsum[t] : 0;
  int incl = wave_incl_scan(v, lane);
  __shared__ int wsum[4];
  if (lane == 63) wsum[t >> 6] = incl;
  __syncthreads();
  int pre = 0;
  for (int j = 0; j < (t >> 6); ++j) pre += wsum[j];
  if (t < nb) boff[t] = pre + incl - v;
}

__global__ __launch_bounds__(256) void scan_apply_kernel(const int* __restrict__ counts,
                                                         const int* __restrict__ boff,
                                                         int* __restrict__ offsets,
                                                         int* __restrict__ cursor,
                                                         float* __restrict__ dinv, int n) {
  int b = blockIdx.x, t = threadIdx.x, lane = t & 63;
  int i = b * 256 + t;
  int c = (i < n) ? counts[i] : 0;
  int incl = wave_incl_scan(c, lane);
  __shared__ int wsum[4];
  if (lane == 63) wsum[t >> 6] = incl;
  __syncthreads();
  int pre = 0;
  for (int j = 0; j < (t >> 6); ++j) pre += wsum[j];
  int excl = boff[b] + pre + incl - c;
  if (i < n) {
    offsets[i] = excl;
    cursor[i] = excl;
    dinv[i] = rsqrtf((float)(c + 1));  // +1 self-loop; deg >= 1 always
    if (i == n - 1) offsets[n] = excl + c;
  }
}

__global__ __launch_bounds__(256) void fill_kernel(const int* __restrict__ src,
                                                   const int* __restrict__ dst, int E,
                                                   int* __restrict__ cursor,
                                                   int* __restrict__ csr) {
  int i = blockIdx.x * 256 + threadIdx.x;
  if (i < E) {
    int d = dst[i];
    int pos = atomicAdd(&cursor[d], 1);
    csr[pos] = src[i];
  }
}

// out[n][64] = A[n][K] @ W[K][64]; K % 32 == 0.
// 64-row tile / block (782 blocks at n=50000 -> ~3/CU uniform), double-buffered LDS,
// register prefetch of tile k+1 during compute of tile k, one barrier per k-tile.
// thread = 4 rows x 4 cols.
__global__ __launch_bounds__(256) void gemm64_kernel(const float* __restrict__ A,
                                                     const float* __restrict__ W,
                                                     float* __restrict__ out, int n, int K) {
  __shared__ float xs[2][64][36];   // pad 36: float4-aligned rows, groups hit distinct banks
  __shared__ float wsm[2][32][64];
  const int t = threadIdx.x;
  const int row0 = blockIdx.x * 64;
  const int c0 = (t & 15) * 4;      // output col group
  const int r0 = (t >> 4) * 4;      // output row group
  // staging indices: x tile 64x32 = 2048 f = 256 thr * 2 float4
  const int lr = t >> 3;            // 0..31
  const int lk = (t & 7) * 4;       // 0..28
  // w tile 32x64 = 2048 f = 2 float4/thread
  const int wk0 = t >> 4;           // 0..15
  const int wc0 = (t & 15) * 4;
  const int wk1 = (t >> 4) + 16;    // 16..31

  float4 xreg[2], wreg[2];
  auto loadg = [&](int k0) {
#pragma unroll
    for (int it = 0; it < 2; ++it) {
      int gr = row0 + lr + it * 32;
      xreg[it] = (gr < n) ? *(const float4*)&A[(size_t)gr * K + k0 + lk]
                          : make_float4(0.f, 0.f, 0.f, 0.f);
    }
    wreg[0] = *(const float4*)&W[(size_t)(k0 + wk0) * 64 + wc0];
    wreg[1] = *(const float4*)&W[(size_t)(k0 + wk1) * 64 + wc0];
  };
  auto stores = [&](int buf) {
#pragma unroll
    for (int it = 0; it < 2; ++it) *(float4*)&xs[buf][lr + it * 32][lk] = xreg[it];
    *(float4*)&wsm[buf][wk0][wc0] = wreg[0];
    *(float4*)&wsm[buf][wk1][wc0] = wreg[1];
  };

  float acc[4][4] = {};
  loadg(0);
  stores(0);
  __syncthreads();
  const int nk = K >> 5;
  for (int kt = 0; kt < nk; ++kt) {
    const int cur = kt & 1;
    if (kt + 1 < nk) loadg((kt + 1) << 5);
#pragma unroll
    for (int kk = 0; kk < 32; kk += 4) {
      float wv[4][4];
#pragma unroll
      for (int j = 0; j < 4; ++j) {
        float4 wj = *(const float4*)&wsm[cur][kk + j][c0];
        wv[j][0] = wj.x; wv[j][1] = wj.y; wv[j][2] = wj.z; wv[j][3] = wj.w;
      }
#pragma unroll
      for (int i = 0; i < 4; ++i) {
        float4 xi = *(const float4*)&xs[cur][r0 + i][kk];
        float xa[4] = {xi.x, xi.y, xi.z, xi.w};
#pragma unroll
        for (int j = 0; j < 4; ++j)
#pragma unroll
          for (int c = 0; c < 4; ++c)
            acc[i][c] = fmaf(xa[j], wv[j][c], acc[i][c]);
      }
    }
    if (kt + 1 < nk) stores(cur ^ 1);
    __syncthreads();
  }
#pragma unroll
  for (int i = 0; i < 4; ++i) {
    int gr = row0 + r0 + i;
    if (gr < n) {
      float4 o = make_float4(acc[i][0], acc[i][1], acc[i][2], acc[i][3]);
      *(float4*)&out[(size_t)gr * 64 + c0] = o;
    }
  }
}

// Aggregation: 16 lanes per node (float4/lane), 4 nodes per wave.
// Edge list chunked by 16: batch-load csr+dinv coalesced, shfl-broadcast within the
// 16-lane group, inner loop fully unrolled so 16 row-gathers pipeline in vmcnt.
// Padded slots use s=0,w=0 (row 0 stays L1-hot; FMA*0 is exact).
__global__ __launch_bounds__(256) void agg_kernel(const float* __restrict__ H,
                                                  const int* __restrict__ offsets,
                                                  const int* __restrict__ csr,
                                                  const float* __restrict__ dinv,
                                                  const float* __restrict__ bias,
                                                  float* __restrict__ out, int n, int do_relu) {
  const int t = threadIdx.x;
  const int lane = t & 63;
  const int sub = lane >> 4;   // node group within wave (0..3)
  const int sl = lane & 15;    // lane within group
  const int v = blockIdx.x * 16 + (t >> 6) * 4 + sub;
  if (v >= n) return;
  const float dv = dinv[v];
  float4 acc = *(const float4*)&H[(size_t)v * 64 + (sl << 2)];
  const float dvv = dv * dv;
  acc.x *= dvv; acc.y *= dvv; acc.z *= dvv; acc.w *= dvv;  // self-loop
  const int e0 = offsets[v], e1 = offsets[v + 1];
  for (int e = e0; e < e1; e += 16) {
    const int idx = e + sl;
    int s_l = 0;
    float w_l = 0.f;
    if (idx < e1) {
      s_l = csr[idx];
      w_l = dinv[s_l];
    }
#pragma unroll
    for (int j = 0; j < 16; ++j) {
      const int srcl = (sub << 4) + j;
      const int s = __shfl(s_l, srcl);
      const float w = __shfl(w_l, srcl) * dv;
      const float4 h4 = *(const float4*)&H[(size_t)s * 64 + (sl << 2)];
      acc.x = fmaf(h4.x, w, acc.x);
      acc.y = fmaf(h4.y, w, acc.y);
      acc.z = fmaf(h4.z, w, acc.z);
      acc.w = fmaf(h4.w, w, acc.w);
    }
  }
  const float4 b4 = *(const float4*)&bias[sl << 2];
  acc.x += b4.x; acc.y += b4.y; acc.z += b4.z; acc.w += b4.w;
  if (do_relu) {
    acc.x = fmaxf(acc.x, 0.f); acc.y = fmaxf(acc.y, 0.f);
    acc.z = fmaxf(acc.z, 0.f); acc.w = fmaxf(acc.w, 0.f);
  }
  *(float4*)&out[(size_t)v * 64 + (sl << 2)] = acc;
}

extern "C" void kernel_launch(void* const* d_in, const int* in_sizes, int n_in,
                              void* d_out, int out_size, void* d_ws, size_t ws_size,
                              hipStream_t stream) {
  const float* x = (const float*)d_in[0];
  const int* ei = (const int*)d_in[1];
  const float* W1 = (const float*)d_in[2];
  const float* b1 = (const float*)d_in[3];
  const float* W2 = (const float*)d_in[4];
  const float* b2 = (const float*)d_in[5];
  float* out = (float*)d_out;

  const int HID = in_sizes[3];           // 64
  const int IN_DIM = in_sizes[2] / HID;  // 512
  const int N = in_sizes[0] / IN_DIM;    // 50000
  const int E = in_sizes[1] / 2;         // 800000
  const int NB = (N + 255) / 256;        // 196 (<=256 for single-block scan)

  uint8_t* p = (uint8_t*)d_ws;
  auto alloc = [&](size_t bytes) {
    void* r = (void*)p;
    p += (bytes + 255) & ~(size_t)255;
    return r;
  };
  int* counts = (int*)alloc((size_t)N * 4);
  int* offsets = (int*)alloc((size_t)(N + 1) * 4);
  int* cursor = (int*)alloc((size_t)N * 4);
  int* bsum = (int*)alloc((size_t)NB * 4);
  int* boff = (int*)alloc((size_t)NB * 4);
  float* dinv = (float*)alloc((size_t)N * 4);
  int* csr = (int*)alloc((size_t)E * 4);
  float* h0 = (float*)alloc((size_t)N * HID * 4);  // reused between layers
  float* h = (float*)alloc((size_t)N * HID * 4);

  const int* srcp = ei;
  const int* dstp = ei + E;

  hipMemsetAsync(counts, 0, (size_t)N * 4, stream);
  hist_kernel<<<(E + 255) / 256, 256, 0, stream>>>(dstp, E, counts);
  bsum_kernel<<<NB, 256, 0, stream>>>(counts, bsum, N);
  scan_bsums_kernel<<<1, 256, 0, stream>>>(bsum, boff, NB);
  scan_apply_kernel<<<NB, 256, 0, stream>>>(counts, boff, offsets, cursor, dinv, N);
  fill_kernel<<<(E + 255) / 256, 256, 0, stream>>>(srcp, dstp, E, cursor, csr);

  gemm64_kernel<<<(N + 63) / 64, 256, 0, stream>>>(x, W1, h0, N, IN_DIM);
  agg_kernel<<<(N + 15) / 16, 256, 0, stream>>>(h0, offsets, csr, dinv, b1, h, N, 1);
  gemm64_kernel<<<(N + 63) / 64, 256, 0, stream>>>(h, W2, h0, N, HID);
  agg_kernel<<<(N + 15) / 16, 256, 0, stream>>>(h0, offsets, csr, dinv, b2, out, N, 0);
}

// Round 3
// 347.499 us; speedup vs baseline: 1.3736x; 1.2435x over previous
//
#include <hip/hip_runtime.h>
#include <stdint.h>

// GCN: z = A_hat( relu( A_hat(x@W1) + b1 ) @ W2 ) + b2, A_hat = D^-1/2 (A+I) D^-1/2
// R3: gemm -> async global_load_lds double-buffer (no VGPR prefetch), 64-row tiles,
//             XOR-swizzled x LDS layout (conflict-free without padding);
//     agg  -> precomputed (src,weight) int2 meta, CSR padded to x8 (zero-weight pads),
//             guard-free unrolled gather pipeline, no DS ops.

__device__ __forceinline__ void async16(void* lds, const void* g) {
  __builtin_amdgcn_global_load_lds(
      (const __attribute__((address_space(1))) uint32_t*)g,
      (__attribute__((address_space(3))) uint32_t*)lds, 16, 0, 0);
}

__device__ __forceinline__ int wave_incl_scan(int v, int lane) {
#pragma unroll
  for (int d = 1; d < 64; d <<= 1) {
    int o = __shfl_up(v, d);
    if (lane >= d) v += o;
  }
  return v;
}

__global__ __launch_bounds__(256) void hist_kernel(const int* __restrict__ dst, int E,
                                                   int* __restrict__ counts) {
  int i = blockIdx.x * 256 + threadIdx.x;
  if (i < E) atomicAdd(&counts[dst[i]], 1);
}

// block sums over PADDED counts (pad to multiple of 8)
__global__ __launch_bounds__(256) void bsum_kernel(const int* __restrict__ counts,
                                                   int* __restrict__ bsum, int n) {
  int i = blockIdx.x * 256 + threadIdx.x;
  int c = (i < n) ? ((counts[i] + 7) & ~7) : 0;
#pragma unroll
  for (int d = 32; d > 0; d >>= 1) c += __shfl_down(c, d);
  __shared__ int ws[4];
  if ((threadIdx.x & 63) == 0) ws[threadIdx.x >> 6] = c;
  __syncthreads();
  if (threadIdx.x == 0) bsum[blockIdx.x] = ws[0] + ws[1] + ws[2] + ws[3];
}

// single block; requires nb <= 256 (nb = ceil(50000/256) = 196)
__global__ __launch_bounds__(256) void scan_bsums_kernel(const int* __restrict__ bsum,
                                                         int* __restrict__ boff, int nb) {
  int t = threadIdx.x, lane = t & 63;
  int v = (t < nb) ? bsum[t] : 0;
  int incl = wave_incl_scan(v, lane);
  __shared__ int wsum[4];
  if (lane == 63) wsum[t >> 6] = incl;
  __syncthreads();
  int pre = 0;
  for (int j = 0; j < (t >> 6); ++j) pre += wsum[j];
  if (t < nb) boff[t] = pre + incl - v;
}

__global__ __launch_bounds__(256) void scan_apply_kernel(const int* __restrict__ counts,
                                                         const int* __restrict__ boff,
                                                         int* __restrict__ offsets,
                                                         int* __restrict__ cursor,
                                                         float* __restrict__ dinv, int n) {
  int b = blockIdx.x, t = threadIdx.x, lane = t & 63;
  int i = b * 256 + t;
  int craw = (i < n) ? counts[i] : 0;
  int c = (craw + 7) & ~7;  // padded degree
  int incl = wave_incl_scan(c, lane);
  __shared__ int wsum[4];
  if (lane == 63) wsum[t >> 6] = incl;
  __syncthreads();
  int pre = 0;
  for (int j = 0; j < (t >> 6); ++j) pre += wsum[j];
  int excl = boff[b] + pre + incl - c;
  if (i < n) {
    offsets[i] = excl;
    cursor[i] = excl;
    dinv[i] = rsqrtf((float)(craw + 1));  // +1 self-loop
    if (i == n - 1) offsets[n] = excl + c;
  }
}

// meta[pos] = {src, dinv[src]*dinv[dst]}; pad slots stay {0, 0.0f} from memset
__global__ __launch_bounds__(256) void fill_kernel(const int* __restrict__ src,
                                                   const int* __restrict__ dst, int E,
                                                   int* __restrict__ cursor,
                                                   const float* __restrict__ dinv,
                                                   int2* __restrict__ meta) {
  int i = blockIdx.x * 256 + threadIdx.x;
  if (i < E) {
    int s = src[i];
    int d = dst[i];
    int pos = atomicAdd(&cursor[d], 1);
    float w = dinv[s] * dinv[d];
    meta[pos] = make_int2(s, __float_as_int(w));
  }
}

// out[n][64] = A[n][K] @ W[K][64]; K % 32 == 0.
// 64-row tile/block; double-buffered LDS fed by global_load_lds (width 16);
// one barrier per k-tile; next tile's loads fly during current tile's compute.
// x LDS layout: slot L holds A[row0 + (L>>3)][k0 + 4*((L&7)^((L>>3)&7))] (XOR swizzle
// -> conflict-free column reads without padding, which global_load_lds forbids).
__global__ __launch_bounds__(256) void gemm64_kernel(const float* __restrict__ A,
                                                     const float* __restrict__ W,
                                                     float* __restrict__ out, int n, int K) {
  __shared__ float xs[2][2048];   // 64 rows x 32 k, 16B slots, swizzled
  __shared__ float wsm[2][2048];  // 32 k x 64 cols, linear (matches global W rows)
  const int t = threadIdx.x;
  const int wv = t >> 6;   // wave 0..3 (uniform within wave)
  const int lane = t & 63;
  const int row0 = blockIdx.x * 64;
  const int c0 = (t & 15) * 4;   // output col group
  const int r0 = (t >> 4) * 4;   // output row group

  auto stage = [&](int k0, int buf) {
#pragma unroll
    for (int c = 0; c < 2; ++c) {
      int L = wv * 128 + c * 64 + lane;
      int row = L >> 3;
      int kc = (L & 7) ^ (row & 7);
      int gr = row0 + row;
      if (gr >= n) gr = n - 1;  // clamp: value discarded by epilogue guard
      async16(&xs[buf][(size_t)(wv * 128 + c * 64) * 4],
              &A[(size_t)gr * K + k0 + (kc << 2)]);
    }
#pragma unroll
    for (int c = 0; c < 2; ++c) {
      int M0 = wv * 128 + c * 64;
      async16(&wsm[buf][(size_t)M0 * 4], &W[(size_t)k0 * 64 + (size_t)(M0 + lane) * 4]);
    }
  };

  float acc[4][4] = {};
  stage(0, 0);
  const int nk = K >> 5;
  for (int kt = 0; kt < nk; ++kt) {
    const int cur = kt & 1;
    __syncthreads();  // drains vmcnt -> buf[cur] ready
    if (kt + 1 < nk) stage((kt + 1) << 5, cur ^ 1);
    const float* xb = xs[cur];
    const float* wb = wsm[cur];
#pragma unroll
    for (int kk = 0; kk < 32; kk += 4) {
      const int kc = kk >> 2;
      float wvv[4][4];
#pragma unroll
      for (int j = 0; j < 4; ++j) {
        float4 wj = *(const float4*)&wb[(kk + j) * 64 + c0];
        wvv[j][0] = wj.x; wvv[j][1] = wj.y; wvv[j][2] = wj.z; wvv[j][3] = wj.w;
      }
#pragma unroll
      for (int i = 0; i < 4; ++i) {
        const int r = r0 + i;
        const int slot = r * 8 + (kc ^ (r & 7));
        float4 xi = *(const float4*)&xb[slot * 4];
        float xa[4] = {xi.x, xi.y, xi.z, xi.w};
#pragma unroll
        for (int j = 0; j < 4; ++j)
#pragma unroll
          for (int c = 0; c < 4; ++c)
            acc[i][c] = fmaf(xa[j], wvv[j][c], acc[i][c]);
      }
    }
  }
#pragma unroll
  for (int i = 0; i < 4; ++i) {
    int gr = row0 + r0 + i;
    if (gr < n) {
      float4 o = make_float4(acc[i][0], acc[i][1], acc[i][2], acc[i][3]);
      *(float4*)&out[(size_t)gr * 64 + c0] = o;
    }
  }
}

// Aggregation: 16 lanes/node (float4 each), 4 nodes/wave. Padded CSR -> guard-free
// chunks of 8: 8 uniform int2 meta loads (same addr across the 16-lane group,
// L1-broadcast) + 8 coalesced 256B row gathers in flight. Pad slots: s=0, w=0.
__global__ __launch_bounds__(256) void agg_kernel(const float* __restrict__ H,
                                                  const int* __restrict__ offsets,
                                                  const int2* __restrict__ meta,
                                                  const float* __restrict__ dinv,
                                                  const float* __restrict__ bias,
                                                  float* __restrict__ out, int n, int do_relu) {
  const int t = threadIdx.x;
  const int sl = t & 15;                              // lane within node group
  const int v = blockIdx.x * 16 + (t >> 4);           // node (16 groups/block)
  if (v >= n) return;
  const float dv = dinv[v];
  float4 acc = *(const float4*)&H[(size_t)v * 64 + (sl << 2)];
  const float dvv = dv * dv;
  acc.x *= dvv; acc.y *= dvv; acc.z *= dvv; acc.w *= dvv;  // self-loop
  const int e0 = offsets[v], e1 = offsets[v + 1];
  for (int e = e0; e < e1; e += 8) {
#pragma unroll
    for (int j = 0; j < 8; ++j) {
      const int2 m = meta[e + j];
      const float w = __int_as_float(m.y);
      const float4 h4 = *(const float4*)&H[(size_t)m.x * 64 + (sl << 2)];
      acc.x = fmaf(h4.x, w, acc.x);
      acc.y = fmaf(h4.y, w, acc.y);
      acc.z = fmaf(h4.z, w, acc.z);
      acc.w = fmaf(h4.w, w, acc.w);
    }
  }
  const float4 b4 = *(const float4*)&bias[sl << 2];
  acc.x += b4.x; acc.y += b4.y; acc.z += b4.z; acc.w += b4.w;
  if (do_relu) {
    acc.x = fmaxf(acc.x, 0.f); acc.y = fmaxf(acc.y, 0.f);
    acc.z = fmaxf(acc.z, 0.f); acc.w = fmaxf(acc.w, 0.f);
  }
  *(float4*)&out[(size_t)v * 64 + (sl << 2)] = acc;
}

extern "C" void kernel_launch(void* const* d_in, const int* in_sizes, int n_in,
                              void* d_out, int out_size, void* d_ws, size_t ws_size,
                              hipStream_t stream) {
  const float* x = (const float*)d_in[0];
  const int* ei = (const int*)d_in[1];
  const float* W1 = (const float*)d_in[2];
  const float* b1 = (const float*)d_in[3];
  const float* W2 = (const float*)d_in[4];
  const float* b2 = (const float*)d_in[5];
  float* out = (float*)d_out;

  const int HID = in_sizes[3];           // 64
  const int IN_DIM = in_sizes[2] / HID;  // 512
  const int N = in_sizes[0] / IN_DIM;    // 50000
  const int E = in_sizes[1] / 2;         // 800000
  const int NB = (N + 255) / 256;        // 196 (<=256 for single-block scan)
  const size_t META_MAX = (size_t)E + 8 * (size_t)N;  // padded-CSR upper bound

  uint8_t* p = (uint8_t*)d_ws;
  auto alloc = [&](size_t bytes) {
    void* r = (void*)p;
    p += (bytes + 255) & ~(size_t)255;
    return r;
  };
  int* counts = (int*)alloc((size_t)N * 4);
  int* offsets = (int*)alloc((size_t)(N + 1) * 4);
  int* cursor = (int*)alloc((size_t)N * 4);
  int* bsum = (int*)alloc((size_t)NB * 4);
  int* boff = (int*)alloc((size_t)NB * 4);
  float* dinv = (float*)alloc((size_t)N * 4);
  int2* meta = (int2*)alloc(META_MAX * 8);
  float* h0 = (float*)alloc((size_t)N * HID * 4);  // reused between layers
  float* h = (float*)alloc((size_t)N * HID * 4);

  const int* srcp = ei;
  const int* dstp = ei + E;

  hipMemsetAsync(counts, 0, (size_t)N * 4, stream);
  hipMemsetAsync(meta, 0, META_MAX * 8, stream);
  hist_kernel<<<(E + 255) / 256, 256, 0, stream>>>(dstp, E, counts);
  bsum_kernel<<<NB, 256, 0, stream>>>(counts, bsum, N);
  scan_bsums_kernel<<<1, 256, 0, stream>>>(bsum, boff, NB);
  scan_apply_kernel<<<NB, 256, 0, stream>>>(counts, boff, offsets, cursor, dinv, N);
  fill_kernel<<<(E + 255) / 256, 256, 0, stream>>>(srcp, dstp, E, cursor, dinv, meta);

  gemm64_kernel<<<(N + 63) / 64, 256, 0, stream>>>(x, W1, h0, N, IN_DIM);
  agg_kernel<<<(N + 15) / 16, 256, 0, stream>>>(h0, offsets, meta, dinv, b1, h, N, 1);
  gemm64_kernel<<<(N + 63) / 64, 256, 0, stream>>>(h, W2, h0, N, HID);
  agg_kernel<<<(N + 15) / 16, 256, 0, stream>>>(h0, offsets, meta, dinv, b2, out, N, 0);
}

// Round 4
// 337.165 us; speedup vs baseline: 1.4157x; 1.0306x over previous
//
#include <hip/hip_runtime.h>
#include <stdint.h>

// GCN: z = A_hat( relu( A_hat(x@W1) + b1 ) @ W2 ) + b2, A_hat = D^-1/2 (A+I) D^-1/2
// R4: gemm -> split-bf16 MFMA (xh/xl, Wh/Wl; 3 MFMA passes ~ f32 precision), no LDS,
//             A-frags direct global->VGPR with in-register hi/lo conversion,
//             B-frags from a pre-fragged L2-resident buffer;
//     agg  -> int4 meta loads + next-chunk prefetch; meta memset replaced by
//             explicit pad writes in scan_apply.

typedef __attribute__((ext_vector_type(8))) short short8;
typedef __attribute__((ext_vector_type(4))) float f32x4;

__device__ __forceinline__ int wave_incl_scan(int v, int lane) {
#pragma unroll
  for (int d = 1; d < 64; d <<= 1) {
    int o = __shfl_up(v, d);
    if (lane >= d) v += o;
  }
  return v;
}

__device__ __forceinline__ uint32_t bf16_rne(float f) {
  uint32_t u = __float_as_uint(f);
  return (u + 0x7FFFu + ((u >> 16) & 1u)) >> 16;
}

__global__ __launch_bounds__(256) void hist_kernel(const int* __restrict__ dst, int E,
                                                   int* __restrict__ counts) {
  int i = blockIdx.x * 256 + threadIdx.x;
  if (i < E) atomicAdd(&counts[dst[i]], 1);
}

// block sums over PADDED counts (pad to multiple of 8)
__global__ __launch_bounds__(256) void bsum_kernel(const int* __restrict__ counts,
                                                   int* __restrict__ bsum, int n) {
  int i = blockIdx.x * 256 + threadIdx.x;
  int c = (i < n) ? ((counts[i] + 7) & ~7) : 0;
#pragma unroll
  for (int d = 32; d > 0; d >>= 1) c += __shfl_down(c, d);
  __shared__ int ws[4];
  if ((threadIdx.x & 63) == 0) ws[threadIdx.x >> 6] = c;
  __syncthreads();
  if (threadIdx.x == 0) bsum[blockIdx.x] = ws[0] + ws[1] + ws[2] + ws[3];
}

// single block; requires nb <= 256 (nb = ceil(50000/256) = 196)
__global__ __launch_bounds__(256) void scan_bsums_kernel(const int* __restrict__ bsum,
                                                         int* __restrict__ boff, int nb) {
  int t = threadIdx.x, lane = t & 63;
  int v = (t < nb) ? bsum[t] : 0;
  int incl = wave_incl_scan(v, lane);
  __shared__ int wsum[4];
  if (lane == 63) wsum[t >> 6] = incl;
  __syncthreads();
  int pre = 0;
  for (int j = 0; j < (t >> 6); ++j) pre += wsum[j];
  if (t < nb) boff[t] = pre + incl - v;
}

__global__ __launch_bounds__(256) void scan_apply_kernel(const int* __restrict__ counts,
                                                         const int* __restrict__ boff,
                                                         int* __restrict__ offsets,
                                                         int* __restrict__ cursor,
                                                         float* __restrict__ dinv,
                                                         int2* __restrict__ meta, int n) {
  int b = blockIdx.x, t = threadIdx.x, lane = t & 63;
  int i = b * 256 + t;
  int craw = (i < n) ? counts[i] : 0;
  int c = (craw + 7) & ~7;  // padded degree
  int incl = wave_incl_scan(c, lane);
  __shared__ int wsum[4];
  if (lane == 63) wsum[t >> 6] = incl;
  __syncthreads();
  int pre = 0;
  for (int j = 0; j < (t >> 6); ++j) pre += wsum[j];
  int excl = boff[b] + pre + incl - c;
  if (i < n) {
    offsets[i] = excl;
    cursor[i] = excl;
    dinv[i] = rsqrtf((float)(craw + 1));  // +1 self-loop
    for (int k = craw; k < c; ++k) meta[excl + k] = make_int2(0, 0);  // zero-weight pads
    if (i == n - 1) offsets[n] = excl + c;
  }
}

// meta[pos] = {src, dinv[src]*dinv[dst]}
__global__ __launch_bounds__(256) void fill_kernel(const int* __restrict__ src,
                                                   const int* __restrict__ dst, int E,
                                                   int* __restrict__ cursor,
                                                   const float* __restrict__ dinv,
                                                   int2* __restrict__ meta) {
  int i = blockIdx.x * 256 + threadIdx.x;
  if (i < E) {
    int s = src[i];
    int d = dst[i];
    int pos = atomicAdd(&cursor[d], 1);
    float w = dinv[s] * dinv[d];
    meta[pos] = make_int2(s, __float_as_int(w));
  }
}

// Pre-frag W (K x 64, f32) into hi/lo bf16 MFMA B-fragments.
// Slot idx = kt*256 + ct*64 + lane; element j = W[kt*32 + (lane>>4)*8 + j][ct*16 + (lane&15)].
// Handles both W1 and W2 in one launch.
__global__ __launch_bounds__(256) void wfrag_kernel(const float* __restrict__ W1,
                                                    const float* __restrict__ W2,
                                                    short8* __restrict__ wh1,
                                                    short8* __restrict__ wl1,
                                                    short8* __restrict__ wh2,
                                                    short8* __restrict__ wl2,
                                                    int K1, int K2) {
  int idx = blockIdx.x * 256 + threadIdx.x;
  int tot1 = (K1 >> 5) * 256;
  int tot2 = (K2 >> 5) * 256;
  const float* W;
  short8 *wh, *wl;
  if (idx < tot1) {
    W = W1; wh = wh1; wl = wl1;
  } else if (idx < tot1 + tot2) {
    idx -= tot1;
    W = W2; wh = wh2; wl = wl2;
  } else {
    return;
  }
  int lane = idx & 63;
  int ct = (idx >> 6) & 3;
  int kt = idx >> 8;
  int m = lane & 15, q = lane >> 4;
  int col = ct * 16 + m;
  short8 h, l;
#pragma unroll
  for (int j = 0; j < 8; ++j) {
    float f = W[(size_t)(kt * 32 + q * 8 + j) * 64 + col];
    uint32_t hb = bf16_rne(f);
    float hf = __uint_as_float(hb << 16);
    float lo = f - hf;
    h[j] = (short)hb;
    l[j] = (short)bf16_rne(lo);
  }
  wh[idx] = h;
  wl[idx] = l;
}

// out[n][64] = A[n][K] @ W[K][64] via split-bf16 MFMA. No LDS, no barriers.
// Block 256 = 4 waves; wave w computes rows [blk*64 + w*16, +16) x all 64 cols.
// A-frag: lane holds A[row0 + (lane&15)][kt*32 + (lane>>4)*8 + j], j=0..7 (two dwordx4),
// converted in-register to bf16 hi/lo. B-frags (hi/lo) from pre-fragged buffer (L2-hot).
// C/D layout: col = lane&15, row = (lane>>4)*4 + reg (m89-verified).
__global__ __launch_bounds__(256) void gemm_mfma_kernel(const float* __restrict__ A,
                                                        const short8* __restrict__ wh,
                                                        const short8* __restrict__ wl,
                                                        float* __restrict__ out, int n, int K) {
  const int t = threadIdx.x;
  const int w = t >> 6, lane = t & 63;
  const int m = lane & 15, q = lane >> 4;
  const int row0 = blockIdx.x * 64 + w * 16;
  int r = row0 + m;
  if (r >= n) r = n - 1;  // clamp; stores are guarded
  const float* ap = A + (size_t)r * K + q * 8;
  const int nkt = K >> 5;
  f32x4 acc0 = 0.f, acc1 = 0.f, acc2 = 0.f, acc3 = 0.f;
  for (int kt = 0; kt < nkt; ++kt) {
    float4 x0 = *(const float4*)(ap);
    float4 x1 = *(const float4*)(ap + 4);
    ap += 32;
    float xf[8] = {x0.x, x0.y, x0.z, x0.w, x1.x, x1.y, x1.z, x1.w};
    short8 ah, al;
#pragma unroll
    for (int j = 0; j < 8; ++j) {
      uint32_t hb = bf16_rne(xf[j]);
      float hf = __uint_as_float(hb << 16);
      float lo = xf[j] - hf;
      ah[j] = (short)hb;
      al[j] = (short)bf16_rne(lo);
    }
    const short8* whp = wh + (size_t)kt * 256 + lane;
    const short8* wlp = wl + (size_t)kt * 256 + lane;
    short8 bh0 = whp[0], bh1 = whp[64], bh2 = whp[128], bh3 = whp[192];
    short8 bl0 = wlp[0], bl1 = wlp[64], bl2 = wlp[128], bl3 = wlp[192];
    acc0 = __builtin_amdgcn_mfma_f32_16x16x32_bf16(ah, bh0, acc0, 0, 0, 0);
    acc1 = __builtin_amdgcn_mfma_f32_16x16x32_bf16(ah, bh1, acc1, 0, 0, 0);
    acc2 = __builtin_amdgcn_mfma_f32_16x16x32_bf16(ah, bh2, acc2, 0, 0, 0);
    acc3 = __builtin_amdgcn_mfma_f32_16x16x32_bf16(ah, bh3, acc3, 0, 0, 0);
    acc0 = __builtin_amdgcn_mfma_f32_16x16x32_bf16(ah, bl0, acc0, 0, 0, 0);
    acc1 = __builtin_amdgcn_mfma_f32_16x16x32_bf16(ah, bl1, acc1, 0, 0, 0);
    acc2 = __builtin_amdgcn_mfma_f32_16x16x32_bf16(ah, bl2, acc2, 0, 0, 0);
    acc3 = __builtin_amdgcn_mfma_f32_16x16x32_bf16(ah, bl3, acc3, 0, 0, 0);
    acc0 = __builtin_amdgcn_mfma_f32_16x16x32_bf16(al, bh0, acc0, 0, 0, 0);
    acc1 = __builtin_amdgcn_mfma_f32_16x16x32_bf16(al, bh1, acc1, 0, 0, 0);
    acc2 = __builtin_amdgcn_mfma_f32_16x16x32_bf16(al, bh2, acc2, 0, 0, 0);
    acc3 = __builtin_amdgcn_mfma_f32_16x16x32_bf16(al, bh3, acc3, 0, 0, 0);
  }
#pragma unroll
  for (int i = 0; i < 4; ++i) {
    int rr = row0 + q * 4 + i;
    if (rr < n) {
      float* op = out + (size_t)rr * 64 + m;
      op[0] = acc0[i];
      op[16] = acc1[i];
      op[32] = acc2[i];
      op[48] = acc3[i];
    }
  }
}

// Aggregation: 16 lanes/node (float4 each). Padded CSR (x8, zero-weight pads) ->
// guard-free chunks of 8 edges = 4 int4 meta loads; next chunk's meta prefetched
// during current chunk's 8 gathers.
__global__ __launch_bounds__(256) void agg_kernel(const float* __restrict__ H,
                                                  const int* __restrict__ offsets,
                                                  const int2* __restrict__ meta,
                                                  const float* __restrict__ dinv,
                                                  const float* __restrict__ bias,
                                                  float* __restrict__ out, int n, int do_relu) {
  const int t = threadIdx.x;
  const int sl = t & 15;
  const int v = blockIdx.x * 16 + (t >> 4);
  if (v >= n) return;
  const float dv = dinv[v];
  float4 acc = *(const float4*)&H[(size_t)v * 64 + (sl << 2)];
  const float dvv = dv * dv;
  acc.x *= dvv; acc.y *= dvv; acc.z *= dvv; acc.w *= dvv;  // self-loop
  const int e0 = offsets[v], e1 = offsets[v + 1];
  const int4* p = (const int4*)(meta + e0);  // e0 % 8 == 0 -> 16B aligned
  int rem = (e1 - e0) >> 3;                  // chunks of 8 edges
  int4 a0, a1, a2, a3;
  if (rem > 0) { a0 = p[0]; a1 = p[1]; a2 = p[2]; a3 = p[3]; }
  auto gather8 = [&](int4 c0, int4 c1, int4 c2, int4 c3) {
    int s[8] = {c0.x, c0.z, c1.x, c1.z, c2.x, c2.z, c3.x, c3.z};
    int wi[8] = {c0.y, c0.w, c1.y, c1.w, c2.y, c2.w, c3.y, c3.w};
#pragma unroll
    for (int j = 0; j < 8; ++j) {
      const float wgt = __int_as_float(wi[j]);
      const float4 h4 = *(const float4*)&H[(size_t)s[j] * 64 + (sl << 2)];
      acc.x = fmaf(h4.x, wgt, acc.x);
      acc.y = fmaf(h4.y, wgt, acc.y);
      acc.z = fmaf(h4.z, wgt, acc.z);
      acc.w = fmaf(h4.w, wgt, acc.w);
    }
  };
  while (rem > 1) {
    int4 b0 = p[4], b1 = p[5], b2 = p[6], b3 = p[7];
    gather8(a0, a1, a2, a3);
    a0 = b0; a1 = b1; a2 = b2; a3 = b3;
    p += 4;
    --rem;
  }
  if (rem == 1) gather8(a0, a1, a2, a3);
  const float4 b4 = *(const float4*)&bias[sl << 2];
  acc.x += b4.x; acc.y += b4.y; acc.z += b4.z; acc.w += b4.w;
  if (do_relu) {
    acc.x = fmaxf(acc.x, 0.f); acc.y = fmaxf(acc.y, 0.f);
    acc.z = fmaxf(acc.z, 0.f); acc.w = fmaxf(acc.w, 0.f);
  }
  *(float4*)&out[(size_t)v * 64 + (sl << 2)] = acc;
}

extern "C" void kernel_launch(void* const* d_in, const int* in_sizes, int n_in,
                              void* d_out, int out_size, void* d_ws, size_t ws_size,
                              hipStream_t stream) {
  const float* x = (const float*)d_in[0];
  const int* ei = (const int*)d_in[1];
  const float* W1 = (const float*)d_in[2];
  const float* b1 = (const float*)d_in[3];
  const float* W2 = (const float*)d_in[4];
  const float* b2 = (const float*)d_in[5];
  float* out = (float*)d_out;

  const int HID = in_sizes[3];           // 64
  const int IN_DIM = in_sizes[2] / HID;  // 512
  const int N = in_sizes[0] / IN_DIM;    // 50000
  const int E = in_sizes[1] / 2;         // 800000
  const int NB = (N + 255) / 256;        // 196 (<=256 for single-block scan)
  const size_t META_MAX = (size_t)E + 8 * (size_t)N;  // padded-CSR upper bound

  uint8_t* p = (uint8_t*)d_ws;
  auto alloc = [&](size_t bytes) {
    void* r = (void*)p;
    p += (bytes + 255) & ~(size_t)255;
    return r;
  };
  int* counts = (int*)alloc((size_t)N * 4);
  int* offsets = (int*)alloc((size_t)(N + 1) * 4);
  int* cursor = (int*)alloc((size_t)N * 4);
  int* bsum = (int*)alloc((size_t)NB * 4);
  int* boff = (int*)alloc((size_t)NB * 4);
  float* dinv = (float*)alloc((size_t)N * 4);
  int2* meta = (int2*)alloc(META_MAX * 8);
  float* h0 = (float*)alloc((size_t)N * HID * 4);  // reused between layers
  float* h = (float*)alloc((size_t)N * HID * 4);
  short8* wh1 = (short8*)alloc((size_t)(IN_DIM >> 5) * 256 * 16);
  short8* wl1 = (short8*)alloc((size_t)(IN_DIM >> 5) * 256 * 16);
  short8* wh2 = (short8*)alloc((size_t)(HID >> 5) * 256 * 16);
  short8* wl2 = (short8*)alloc((size_t)(HID >> 5) * 256 * 16);

  const int* srcp = ei;
  const int* dstp = ei + E;

  hipMemsetAsync(counts, 0, (size_t)N * 4, stream);
  hist_kernel<<<(E + 255) / 256, 256, 0, stream>>>(dstp, E, counts);
  bsum_kernel<<<NB, 256, 0, stream>>>(counts, bsum, N);
  scan_bsums_kernel<<<1, 256, 0, stream>>>(bsum, boff, NB);
  scan_apply_kernel<<<NB, 256, 0, stream>>>(counts, boff, offsets, cursor, dinv, meta, N);
  fill_kernel<<<(E + 255) / 256, 256, 0, stream>>>(srcp, dstp, E, cursor, dinv, meta);

  const int wtot = (IN_DIM >> 5) * 256 + (HID >> 5) * 256;
  wfrag_kernel<<<(wtot + 255) / 256, 256, 0, stream>>>(W1, W2, wh1, wl1, wh2, wl2,
                                                       IN_DIM, HID);

  gemm_mfma_kernel<<<(N + 63) / 64, 256, 0, stream>>>(x, wh1, wl1, h0, N, IN_DIM);
  agg_kernel<<<(N + 15) / 16, 256, 0, stream>>>(h0, offsets, meta, dinv, b1, h, N, 1);
  gemm_mfma_kernel<<<(N + 63) / 64, 256, 0, stream>>>(h, wh2, wl2, h0, N, HID);
  agg_kernel<<<(N + 15) / 16, 256, 0, stream>>>(h0, offsets, meta, dinv, b2, out, N, 0);
}

// Round 5
// 316.283 us; speedup vs baseline: 1.5091x; 1.0660x over previous
//
#include <hip/hip_runtime.h>
#include <stdint.h>

// GCN: z = A_hat( relu( A_hat(x@W1) + b1 ) @ W2 ) + b2, A_hat = D^-1/2 (A+I) D^-1/2
// R5: gemm -> explicit register double-buffer (prefetch next k-tile's A+B during
//             current tile's MFMAs) to fix the latency-serial loop (R4: MfmaUtil 5.7%,
//             VGPR 44 -> no compiler pipelining);
//             gemm now writes bf16 (its only consumer is agg);
//     agg  -> gathers bf16 rows (128 B/edge instead of 256) -> halves L3 gather bytes.

typedef __attribute__((ext_vector_type(8))) short short8;
typedef __attribute__((ext_vector_type(4))) float f32x4;

__device__ __forceinline__ int wave_incl_scan(int v, int lane) {
#pragma unroll
  for (int d = 1; d < 64; d <<= 1) {
    int o = __shfl_up(v, d);
    if (lane >= d) v += o;
  }
  return v;
}

__device__ __forceinline__ uint32_t bf16_rne(float f) {
  uint32_t u = __float_as_uint(f);
  return (u + 0x7FFFu + ((u >> 16) & 1u)) >> 16;
}

__device__ __forceinline__ float4 bf2x4(uint2 u) {
  return make_float4(__uint_as_float(u.x << 16), __uint_as_float(u.x & 0xFFFF0000u),
                     __uint_as_float(u.y << 16), __uint_as_float(u.y & 0xFFFF0000u));
}

__global__ __launch_bounds__(256) void hist_kernel(const int* __restrict__ dst, int E,
                                                   int* __restrict__ counts) {
  int i = blockIdx.x * 256 + threadIdx.x;
  if (i < E) atomicAdd(&counts[dst[i]], 1);
}

// block sums over PADDED counts (pad to multiple of 8)
__global__ __launch_bounds__(256) void bsum_kernel(const int* __restrict__ counts,
                                                   int* __restrict__ bsum, int n) {
  int i = blockIdx.x * 256 + threadIdx.x;
  int c = (i < n) ? ((counts[i] + 7) & ~7) : 0;
#pragma unroll
  for (int d = 32; d > 0; d >>= 1) c += __shfl_down(c, d);
  __shared__ int ws[4];
  if ((threadIdx.x & 63) == 0) ws[threadIdx.x >> 6] = c;
  __syncthreads();
  if (threadIdx.x == 0) bsum[blockIdx.x] = ws[0] + ws[1] + ws[2] + ws[3];
}

// single block; requires nb <= 256 (nb = ceil(50000/256) = 196)
__global__ __launch_bounds__(256) void scan_bsums_kernel(const int* __restrict__ bsum,
                                                         int* __restrict__ boff, int nb) {
  int t = threadIdx.x, lane = t & 63;
  int v = (t < nb) ? bsum[t] : 0;
  int incl = wave_incl_scan(v, lane);
  __shared__ int wsum[4];
  if (lane == 63) wsum[t >> 6] = incl;
  __syncthreads();
  int pre = 0;
  for (int j = 0; j < (t >> 6); ++j) pre += wsum[j];
  if (t < nb) boff[t] = pre + incl - v;
}

__global__ __launch_bounds__(256) void scan_apply_kernel(const int* __restrict__ counts,
                                                         const int* __restrict__ boff,
                                                         int* __restrict__ offsets,
                                                         int* __restrict__ cursor,
                                                         float* __restrict__ dinv,
                                                         int2* __restrict__ meta, int n) {
  int b = blockIdx.x, t = threadIdx.x, lane = t & 63;
  int i = b * 256 + t;
  int craw = (i < n) ? counts[i] : 0;
  int c = (craw + 7) & ~7;  // padded degree
  int incl = wave_incl_scan(c, lane);
  __shared__ int wsum[4];
  if (lane == 63) wsum[t >> 6] = incl;
  __syncthreads();
  int pre = 0;
  for (int j = 0; j < (t >> 6); ++j) pre += wsum[j];
  int excl = boff[b] + pre + incl - c;
  if (i < n) {
    offsets[i] = excl;
    cursor[i] = excl;
    dinv[i] = rsqrtf((float)(craw + 1));  // +1 self-loop
    for (int k = craw; k < c; ++k) meta[excl + k] = make_int2(0, 0);  // zero-weight pads
    if (i == n - 1) offsets[n] = excl + c;
  }
}

// meta[pos] = {src, dinv[src]*dinv[dst]}
__global__ __launch_bounds__(256) void fill_kernel(const int* __restrict__ src,
                                                   const int* __restrict__ dst, int E,
                                                   int* __restrict__ cursor,
                                                   const float* __restrict__ dinv,
                                                   int2* __restrict__ meta) {
  int i = blockIdx.x * 256 + threadIdx.x;
  if (i < E) {
    int s = src[i];
    int d = dst[i];
    int pos = atomicAdd(&cursor[d], 1);
    float w = dinv[s] * dinv[d];
    meta[pos] = make_int2(s, __float_as_int(w));
  }
}

// Pre-frag W (K x 64, f32) into hi/lo bf16 MFMA B-fragments.
// Slot idx = kt*256 + ct*64 + lane; element j = W[kt*32 + (lane>>4)*8 + j][ct*16 + (lane&15)].
__global__ __launch_bounds__(256) void wfrag_kernel(const float* __restrict__ W1,
                                                    const float* __restrict__ W2,
                                                    short8* __restrict__ wh1,
                                                    short8* __restrict__ wl1,
                                                    short8* __restrict__ wh2,
                                                    short8* __restrict__ wl2,
                                                    int K1, int K2) {
  int idx = blockIdx.x * 256 + threadIdx.x;
  int tot1 = (K1 >> 5) * 256;
  int tot2 = (K2 >> 5) * 256;
  const float* W;
  short8 *wh, *wl;
  if (idx < tot1) {
    W = W1; wh = wh1; wl = wl1;
  } else if (idx < tot1 + tot2) {
    idx -= tot1;
    W = W2; wh = wh2; wl = wl2;
  } else {
    return;
  }
  int lane = idx & 63;
  int ct = (idx >> 6) & 3;
  int kt = idx >> 8;
  int m = lane & 15, q = lane >> 4;
  int col = ct * 16 + m;
  short8 h, l;
#pragma unroll
  for (int j = 0; j < 8; ++j) {
    float f = W[(size_t)(kt * 32 + q * 8 + j) * 64 + col];
    uint32_t hb = bf16_rne(f);
    float hf = __uint_as_float(hb << 16);
    float lo = f - hf;
    h[j] = (short)hb;
    l[j] = (short)bf16_rne(lo);
  }
  wh[idx] = h;
  wl[idx] = l;
}

// outb[n][64] (bf16) = A[n][K] @ W[K][64] via split-bf16 MFMA. No LDS, no barriers.
// Explicit register double-buffer: next k-tile's A (2xfloat4) + B (8xshort8) loads
// issue before the current tile's MFMAs -> one full tile of latency tolerance/wave.
// C/D layout: col = lane&15, row = (lane>>4)*4 + reg (m89-verified).
__global__ __launch_bounds__(256) void gemm_mfma_kernel(const float* __restrict__ A,
                                                        const short8* __restrict__ wh,
                                                        const short8* __restrict__ wl,
                                                        ushort* __restrict__ outb,
                                                        int n, int K) {
  const int t = threadIdx.x;
  const int w = t >> 6, lane = t & 63;
  const int m = lane & 15, q = lane >> 4;
  const int row0 = blockIdx.x * 64 + w * 16;
  int r = row0 + m;
  if (r >= n) r = n - 1;  // clamp; stores are guarded
  const float* ap = A + (size_t)r * K + q * 8;
  const short8* whp = wh + lane;
  const short8* wlp = wl + lane;
  const int nkt = K >> 5;
  f32x4 acc0 = 0.f, acc1 = 0.f, acc2 = 0.f, acc3 = 0.f;

  float4 x0 = *(const float4*)(ap);
  float4 x1 = *(const float4*)(ap + 4);
  short8 bh0 = whp[0], bh1 = whp[64], bh2 = whp[128], bh3 = whp[192];
  short8 bl0 = wlp[0], bl1 = wlp[64], bl2 = wlp[128], bl3 = wlp[192];

  auto compute = [&]() {
    float xf[8] = {x0.x, x0.y, x0.z, x0.w, x1.x, x1.y, x1.z, x1.w};
    short8 ah, al;
#pragma unroll
    for (int j = 0; j < 8; ++j) {
      uint32_t hb = bf16_rne(xf[j]);
      float hf = __uint_as_float(hb << 16);
      float lo = xf[j] - hf;
      ah[j] = (short)hb;
      al[j] = (short)bf16_rne(lo);
    }
    acc0 = __builtin_amdgcn_mfma_f32_16x16x32_bf16(ah, bh0, acc0, 0, 0, 0);
    acc1 = __builtin_amdgcn_mfma_f32_16x16x32_bf16(ah, bh1, acc1, 0, 0, 0);
    acc2 = __builtin_amdgcn_mfma_f32_16x16x32_bf16(ah, bh2, acc2, 0, 0, 0);
    acc3 = __builtin_amdgcn_mfma_f32_16x16x32_bf16(ah, bh3, acc3, 0, 0, 0);
    acc0 = __builtin_amdgcn_mfma_f32_16x16x32_bf16(ah, bl0, acc0, 0, 0, 0);
    acc1 = __builtin_amdgcn_mfma_f32_16x16x32_bf16(ah, bl1, acc1, 0, 0, 0);
    acc2 = __builtin_amdgcn_mfma_f32_16x16x32_bf16(ah, bl2, acc2, 0, 0, 0);
    acc3 = __builtin_amdgcn_mfma_f32_16x16x32_bf16(ah, bl3, acc3, 0, 0, 0);
    acc0 = __builtin_amdgcn_mfma_f32_16x16x32_bf16(al, bh0, acc0, 0, 0, 0);
    acc1 = __builtin_amdgcn_mfma_f32_16x16x32_bf16(al, bh1, acc1, 0, 0, 0);
    acc2 = __builtin_amdgcn_mfma_f32_16x16x32_bf16(al, bh2, acc2, 0, 0, 0);
    acc3 = __builtin_amdgcn_mfma_f32_16x16x32_bf16(al, bh3, acc3, 0, 0, 0);
  };

  for (int kt = 0; kt < nkt - 1; ++kt) {
    // prefetch k-tile kt+1 (A first so the convert's waitcnt releases before B's)
    const float* ap2 = ap + 32;
    float4 nx0 = *(const float4*)(ap2);
    float4 nx1 = *(const float4*)(ap2 + 4);
    const short8* whn = whp + 256;
    const short8* wln = wlp + 256;
    short8 nh0 = whn[0], nh1 = whn[64], nh2 = whn[128], nh3 = whn[192];
    short8 nl0 = wln[0], nl1 = wln[64], nl2 = wln[128], nl3 = wln[192];
    compute();
    x0 = nx0; x1 = nx1;
    bh0 = nh0; bh1 = nh1; bh2 = nh2; bh3 = nh3;
    bl0 = nl0; bl1 = nl1; bl2 = nl2; bl3 = nl3;
    ap = ap2; whp = whn; wlp = wln;
  }
  compute();  // last tile

#pragma unroll
  for (int i = 0; i < 4; ++i) {
    int rr = row0 + q * 4 + i;
    if (rr < n) {
      ushort* op = outb + (size_t)rr * 64 + m;
      op[0]  = (ushort)bf16_rne(acc0[i]);
      op[16] = (ushort)bf16_rne(acc1[i]);
      op[32] = (ushort)bf16_rne(acc2[i]);
      op[48] = (ushort)bf16_rne(acc3[i]);
    }
  }
}

// Aggregation over bf16 rows: 16 lanes/node, uint2 (4 bf16) per lane -> 128 B/edge.
// Padded CSR (x8, zero-weight pads) -> guard-free chunks of 8 edges = 4 int4 meta
// loads; next chunk's meta prefetched during current chunk's gathers. f32 output.
__global__ __launch_bounds__(256) void agg_kernel(const ushort* __restrict__ H,
                                                  const int* __restrict__ offsets,
                                                  const int2* __restrict__ meta,
                                                  const float* __restrict__ dinv,
                                                  const float* __restrict__ bias,
                                                  float* __restrict__ out, int n, int do_relu) {
  const int t = threadIdx.x;
  const int sl = t & 15;
  const int v = blockIdx.x * 16 + (t >> 4);
  if (v >= n) return;
  const float dv = dinv[v];
  float4 hv = bf2x4(*(const uint2*)&H[(size_t)v * 64 + (sl << 2)]);
  const float dvv = dv * dv;
  float4 acc = make_float4(hv.x * dvv, hv.y * dvv, hv.z * dvv, hv.w * dvv);  // self-loop
  const int e0 = offsets[v], e1 = offsets[v + 1];
  const int4* p = (const int4*)(meta + e0);  // e0 % 8 == 0 -> 16B aligned
  int rem = (e1 - e0) >> 3;                  // chunks of 8 edges
  int4 a0, a1, a2, a3;
  if (rem > 0) { a0 = p[0]; a1 = p[1]; a2 = p[2]; a3 = p[3]; }
  auto gather8 = [&](int4 c0, int4 c1, int4 c2, int4 c3) {
    int s[8] = {c0.x, c0.z, c1.x, c1.z, c2.x, c2.z, c3.x, c3.z};
    int wi[8] = {c0.y, c0.w, c1.y, c1.w, c2.y, c2.w, c3.y, c3.w};
    uint2 raw[8];
#pragma unroll
    for (int j = 0; j < 8; ++j) raw[j] = *(const uint2*)&H[(size_t)s[j] * 64 + (sl << 2)];
#pragma unroll
    for (int j = 0; j < 8; ++j) {
      const float wgt = __int_as_float(wi[j]);
      const float4 h4 = bf2x4(raw[j]);
      acc.x = fmaf(h4.x, wgt, acc.x);
      acc.y = fmaf(h4.y, wgt, acc.y);
      acc.z = fmaf(h4.z, wgt, acc.z);
      acc.w = fmaf(h4.w, wgt, acc.w);
    }
  };
  while (rem > 1) {
    int4 b0 = p[4], b1 = p[5], b2 = p[6], b3 = p[7];
    gather8(a0, a1, a2, a3);
    a0 = b0; a1 = b1; a2 = b2; a3 = b3;
    p += 4;
    --rem;
  }
  if (rem == 1) gather8(a0, a1, a2, a3);
  const float4 b4 = *(const float4*)&bias[sl << 2];
  acc.x += b4.x; acc.y += b4.y; acc.z += b4.z; acc.w += b4.w;
  if (do_relu) {
    acc.x = fmaxf(acc.x, 0.f); acc.y = fmaxf(acc.y, 0.f);
    acc.z = fmaxf(acc.z, 0.f); acc.w = fmaxf(acc.w, 0.f);
  }
  *(float4*)&out[(size_t)v * 64 + (sl << 2)] = acc;
}

extern "C" void kernel_launch(void* const* d_in, const int* in_sizes, int n_in,
                              void* d_out, int out_size, void* d_ws, size_t ws_size,
                              hipStream_t stream) {
  const float* x = (const float*)d_in[0];
  const int* ei = (const int*)d_in[1];
  const float* W1 = (const float*)d_in[2];
  const float* b1 = (const float*)d_in[3];
  const float* W2 = (const float*)d_in[4];
  const float* b2 = (const float*)d_in[5];
  float* out = (float*)d_out;

  const int HID = in_sizes[3];           // 64
  const int IN_DIM = in_sizes[2] / HID;  // 512
  const int N = in_sizes[0] / IN_DIM;    // 50000
  const int E = in_sizes[1] / 2;         // 800000
  const int NB = (N + 255) / 256;        // 196 (<=256 for single-block scan)
  const size_t META_MAX = (size_t)E + 8 * (size_t)N;  // padded-CSR upper bound

  uint8_t* p = (uint8_t*)d_ws;
  auto alloc = [&](size_t bytes) {
    void* r = (void*)p;
    p += (bytes + 255) & ~(size_t)255;
    return r;
  };
  int* counts = (int*)alloc((size_t)N * 4);
  int* offsets = (int*)alloc((size_t)(N + 1) * 4);
  int* cursor = (int*)alloc((size_t)N * 4);
  int* bsum = (int*)alloc((size_t)NB * 4);
  int* boff = (int*)alloc((size_t)NB * 4);
  float* dinv = (float*)alloc((size_t)N * 4);
  int2* meta = (int2*)alloc(META_MAX * 8);
  ushort* hb = (ushort*)alloc((size_t)N * HID * 2);  // bf16 gemm out (reused L1/L2)
  float* h = (float*)alloc((size_t)N * HID * 4);     // f32 agg1 out
  short8* wh1 = (short8*)alloc((size_t)(IN_DIM >> 5) * 256 * 16);
  short8* wl1 = (short8*)alloc((size_t)(IN_DIM >> 5) * 256 * 16);
  short8* wh2 = (short8*)alloc((size_t)(HID >> 5) * 256 * 16);
  short8* wl2 = (short8*)alloc((size_t)(HID >> 5) * 256 * 16);

  const int* srcp = ei;
  const int* dstp = ei + E;

  hipMemsetAsync(counts, 0, (size_t)N * 4, stream);
  hist_kernel<<<(E + 255) / 256, 256, 0, stream>>>(dstp, E, counts);
  bsum_kernel<<<NB, 256, 0, stream>>>(counts, bsum, N);
  scan_bsums_kernel<<<1, 256, 0, stream>>>(bsum, boff, NB);
  scan_apply_kernel<<<NB, 256, 0, stream>>>(counts, boff, offsets, cursor, dinv, meta, N);
  fill_kernel<<<(E + 255) / 256, 256, 0, stream>>>(srcp, dstp, E, cursor, dinv, meta);

  const int wtot = (IN_DIM >> 5) * 256 + (HID >> 5) * 256;
  wfrag_kernel<<<(wtot + 255) / 256, 256, 0, stream>>>(W1, W2, wh1, wl1, wh2, wl2,
                                                       IN_DIM, HID);

  gemm_mfma_kernel<<<(N + 63) / 64, 256, 0, stream>>>(x, wh1, wl1, hb, N, IN_DIM);
  agg_kernel<<<(N + 15) / 16, 256, 0, stream>>>(hb, offsets, meta, dinv, b1, h, N, 1);
  gemm_mfma_kernel<<<(N + 63) / 64, 256, 0, stream>>>(h, wh2, wl2, hb, N, HID);
  agg_kernel<<<(N + 15) / 16, 256, 0, stream>>>(hb, offsets, meta, dinv, b2, out, N, 0);
}

// Round 6
// 301.228 us; speedup vs baseline: 1.5845x; 1.0500x over previous
//
#include <hip/hip_runtime.h>
#include <stdint.h>

// GCN: z = A_hat( relu( A_hat(x@W1) + b1 ) @ W2 ) + b2, A_hat = D^-1/2 (A+I) D^-1/2
// R6: gemm -> 32 rows/wave (two 16-row MFMA groups share B-frags; halves B L2 traffic
//             per MFMA, doubles per-tile compute issue for the depth-1 prefetch);
//     agg  -> 8 lanes/node (uint4 of 8 bf16 per lane): 64 gathers in flight per wave.

typedef __attribute__((ext_vector_type(8))) short short8;
typedef __attribute__((ext_vector_type(4))) float f32x4;

__device__ __forceinline__ int wave_incl_scan(int v, int lane) {
#pragma unroll
  for (int d = 1; d < 64; d <<= 1) {
    int o = __shfl_up(v, d);
    if (lane >= d) v += o;
  }
  return v;
}

__device__ __forceinline__ uint32_t bf16_rne(float f) {
  uint32_t u = __float_as_uint(f);
  return (u + 0x7FFFu + ((u >> 16) & 1u)) >> 16;
}

__global__ __launch_bounds__(256) void hist_kernel(const int* __restrict__ dst, int E,
                                                   int* __restrict__ counts) {
  int i = blockIdx.x * 256 + threadIdx.x;
  if (i < E) atomicAdd(&counts[dst[i]], 1);
}

// block sums over PADDED counts (pad to multiple of 8)
__global__ __launch_bounds__(256) void bsum_kernel(const int* __restrict__ counts,
                                                   int* __restrict__ bsum, int n) {
  int i = blockIdx.x * 256 + threadIdx.x;
  int c = (i < n) ? ((counts[i] + 7) & ~7) : 0;
#pragma unroll
  for (int d = 32; d > 0; d >>= 1) c += __shfl_down(c, d);
  __shared__ int ws[4];
  if ((threadIdx.x & 63) == 0) ws[threadIdx.x >> 6] = c;
  __syncthreads();
  if (threadIdx.x == 0) bsum[blockIdx.x] = ws[0] + ws[1] + ws[2] + ws[3];
}

// single block; requires nb <= 256 (nb = ceil(50000/256) = 196)
__global__ __launch_bounds__(256) void scan_bsums_kernel(const int* __restrict__ bsum,
                                                         int* __restrict__ boff, int nb) {
  int t = threadIdx.x, lane = t & 63;
  int v = (t < nb) ? bsum[t] : 0;
  int incl = wave_incl_scan(v, lane);
  __shared__ int wsum[4];
  if (lane == 63) wsum[t >> 6] = incl;
  __syncthreads();
  int pre = 0;
  for (int j = 0; j < (t >> 6); ++j) pre += wsum[j];
  if (t < nb) boff[t] = pre + incl - v;
}

__global__ __launch_bounds__(256) void scan_apply_kernel(const int* __restrict__ counts,
                                                         const int* __restrict__ boff,
                                                         int* __restrict__ offsets,
                                                         int* __restrict__ cursor,
                                                         float* __restrict__ dinv,
                                                         int2* __restrict__ meta, int n) {
  int b = blockIdx.x, t = threadIdx.x, lane = t & 63;
  int i = b * 256 + t;
  int craw = (i < n) ? counts[i] : 0;
  int c = (craw + 7) & ~7;  // padded degree
  int incl = wave_incl_scan(c, lane);
  __shared__ int wsum[4];
  if (lane == 63) wsum[t >> 6] = incl;
  __syncthreads();
  int pre = 0;
  for (int j = 0; j < (t >> 6); ++j) pre += wsum[j];
  int excl = boff[b] + pre + incl - c;
  if (i < n) {
    offsets[i] = excl;
    cursor[i] = excl;
    dinv[i] = rsqrtf((float)(craw + 1));  // +1 self-loop
    for (int k = craw; k < c; ++k) meta[excl + k] = make_int2(0, 0);  // zero-weight pads
    if (i == n - 1) offsets[n] = excl + c;
  }
}

// meta[pos] = {src, dinv[src]*dinv[dst]}
__global__ __launch_bounds__(256) void fill_kernel(const int* __restrict__ src,
                                                   const int* __restrict__ dst, int E,
                                                   int* __restrict__ cursor,
                                                   const float* __restrict__ dinv,
                                                   int2* __restrict__ meta) {
  int i = blockIdx.x * 256 + threadIdx.x;
  if (i < E) {
    int s = src[i];
    int d = dst[i];
    int pos = atomicAdd(&cursor[d], 1);
    float w = dinv[s] * dinv[d];
    meta[pos] = make_int2(s, __float_as_int(w));
  }
}

// Pre-frag W (K x 64, f32) into hi/lo bf16 MFMA B-fragments.
// Slot idx = kt*256 + ct*64 + lane; element j = W[kt*32 + (lane>>4)*8 + j][ct*16 + (lane&15)].
__global__ __launch_bounds__(256) void wfrag_kernel(const float* __restrict__ W1,
                                                    const float* __restrict__ W2,
                                                    short8* __restrict__ wh1,
                                                    short8* __restrict__ wl1,
                                                    short8* __restrict__ wh2,
                                                    short8* __restrict__ wl2,
                                                    int K1, int K2) {
  int idx = blockIdx.x * 256 + threadIdx.x;
  int tot1 = (K1 >> 5) * 256;
  int tot2 = (K2 >> 5) * 256;
  const float* W;
  short8 *wh, *wl;
  if (idx < tot1) {
    W = W1; wh = wh1; wl = wl1;
  } else if (idx < tot1 + tot2) {
    idx -= tot1;
    W = W2; wh = wh2; wl = wl2;
  } else {
    return;
  }
  int lane = idx & 63;
  int ct = (idx >> 6) & 3;
  int kt = idx >> 8;
  int m = lane & 15, q = lane >> 4;
  int col = ct * 16 + m;
  short8 h, l;
#pragma unroll
  for (int j = 0; j < 8; ++j) {
    float f = W[(size_t)(kt * 32 + q * 8 + j) * 64 + col];
    uint32_t hb = bf16_rne(f);
    float hf = __uint_as_float(hb << 16);
    float lo = f - hf;
    h[j] = (short)hb;
    l[j] = (short)bf16_rne(lo);
  }
  wh[idx] = h;
  wl[idx] = l;
}

// outb[n][64] (bf16) = A[n][K] @ W[K][64] via split-bf16 MFMA. No LDS, no barriers.
// 128 rows/block; each wave does 32 rows = two 16-row groups sharing every B-frag.
// Register double-buffer: next k-tile's A (4xfloat4) + B (8xshort8) prefetched during
// the current tile's 24 MFMAs. C/D layout: col=lane&15, row=(lane>>4)*4+reg.
__global__ __launch_bounds__(256) void gemm_mfma_kernel(const float* __restrict__ A,
                                                        const short8* __restrict__ wh,
                                                        const short8* __restrict__ wl,
                                                        ushort* __restrict__ outb,
                                                        int n, int K) {
  const int t = threadIdx.x;
  const int w = t >> 6, lane = t & 63;
  const int m = lane & 15, q = lane >> 4;
  const int row0 = blockIdx.x * 128 + w * 32;
  int r0 = row0 + m;
  int r1 = row0 + 16 + m;
  if (r0 >= n) r0 = n - 1;  // clamp; stores are guarded
  if (r1 >= n) r1 = n - 1;
  const float* ap0 = A + (size_t)r0 * K + q * 8;
  const float* ap1 = A + (size_t)r1 * K + q * 8;
  const short8* whp = wh + lane;
  const short8* wlp = wl + lane;
  const int nkt = K >> 5;
  f32x4 acc[2][4];
#pragma unroll
  for (int g = 0; g < 2; ++g)
#pragma unroll
    for (int c = 0; c < 4; ++c) acc[g][c] = 0.f;

  float4 xa0 = *(const float4*)(ap0);
  float4 xa1 = *(const float4*)(ap0 + 4);
  float4 xb0 = *(const float4*)(ap1);
  float4 xb1 = *(const float4*)(ap1 + 4);
  short8 bh[4] = {whp[0], whp[64], whp[128], whp[192]};
  short8 bl[4] = {wlp[0], wlp[64], wlp[128], wlp[192]};

  auto cvt = [&](const float4& u0, const float4& u1, short8& hi, short8& lo) {
    float xf[8] = {u0.x, u0.y, u0.z, u0.w, u1.x, u1.y, u1.z, u1.w};
#pragma unroll
    for (int j = 0; j < 8; ++j) {
      uint32_t hb = bf16_rne(xf[j]);
      float hf = __uint_as_float(hb << 16);
      hi[j] = (short)hb;
      lo[j] = (short)bf16_rne(xf[j] - hf);
    }
  };
  auto compute = [&]() {
    short8 ah0, al0, ah1, al1;
    cvt(xa0, xa1, ah0, al0);
    cvt(xb0, xb1, ah1, al1);
#pragma unroll
    for (int c = 0; c < 4; ++c) {
      acc[0][c] = __builtin_amdgcn_mfma_f32_16x16x32_bf16(ah0, bh[c], acc[0][c], 0, 0, 0);
      acc[1][c] = __builtin_amdgcn_mfma_f32_16x16x32_bf16(ah1, bh[c], acc[1][c], 0, 0, 0);
    }
#pragma unroll
    for (int c = 0; c < 4; ++c) {
      acc[0][c] = __builtin_amdgcn_mfma_f32_16x16x32_bf16(ah0, bl[c], acc[0][c], 0, 0, 0);
      acc[1][c] = __builtin_amdgcn_mfma_f32_16x16x32_bf16(ah1, bl[c], acc[1][c], 0, 0, 0);
    }
#pragma unroll
    for (int c = 0; c < 4; ++c) {
      acc[0][c] = __builtin_amdgcn_mfma_f32_16x16x32_bf16(al0, bh[c], acc[0][c], 0, 0, 0);
      acc[1][c] = __builtin_amdgcn_mfma_f32_16x16x32_bf16(al1, bh[c], acc[1][c], 0, 0, 0);
    }
  };

  for (int kt = 0; kt < nkt - 1; ++kt) {
    const float* an0 = ap0 + 32;
    const float* an1 = ap1 + 32;
    float4 nxa0 = *(const float4*)(an0);
    float4 nxa1 = *(const float4*)(an0 + 4);
    float4 nxb0 = *(const float4*)(an1);
    float4 nxb1 = *(const float4*)(an1 + 4);
    const short8* whn = whp + 256;
    const short8* wln = wlp + 256;
    short8 nh[4] = {whn[0], whn[64], whn[128], whn[192]};
    short8 nl[4] = {wln[0], wln[64], wln[128], wln[192]};
    compute();
    xa0 = nxa0; xa1 = nxa1; xb0 = nxb0; xb1 = nxb1;
#pragma unroll
    for (int c = 0; c < 4; ++c) { bh[c] = nh[c]; bl[c] = nl[c]; }
    ap0 = an0; ap1 = an1; whp = whn; wlp = wln;
  }
  compute();  // last tile

#pragma unroll
  for (int g = 0; g < 2; ++g)
#pragma unroll
    for (int i = 0; i < 4; ++i) {
      int rr = row0 + g * 16 + q * 4 + i;
      if (rr < n) {
        ushort* op = outb + (size_t)rr * 64 + m;
        op[0]  = (ushort)bf16_rne(acc[g][0][i]);
        op[16] = (ushort)bf16_rne(acc[g][1][i]);
        op[32] = (ushort)bf16_rne(acc[g][2][i]);
        op[48] = (ushort)bf16_rne(acc[g][3][i]);
      }
    }
}

// Aggregation over bf16 rows: 8 lanes/node, uint4 (8 bf16) per lane -> 128 B/edge,
// 8 nodes/wave -> 64 gathers in flight/wave. Padded CSR (x8, zero-weight pads) ->
// guard-free chunks of 8 edges = 4 uniform int4 meta loads (8-lane L1 broadcast);
// next chunk's meta prefetched during current chunk's gathers. f32 output.
__global__ __launch_bounds__(256) void agg_kernel(const ushort* __restrict__ H,
                                                  const int* __restrict__ offsets,
                                                  const int2* __restrict__ meta,
                                                  const float* __restrict__ dinv,
                                                  const float* __restrict__ bias,
                                                  float* __restrict__ out, int n, int do_relu) {
  const int t = threadIdx.x;
  const int sl = t & 7;
  const int v = blockIdx.x * 32 + (t >> 3);
  if (v >= n) return;
  const float dv = dinv[v];
  const float dvv = dv * dv;
  float acc[8];
  {
    uint4 hv = *(const uint4*)&H[(size_t)v * 64 + (sl << 3)];
    uint32_t u[4] = {hv.x, hv.y, hv.z, hv.w};
#pragma unroll
    for (int j = 0; j < 4; ++j) {
      acc[2 * j]     = __uint_as_float(u[j] << 16) * dvv;
      acc[2 * j + 1] = __uint_as_float(u[j] & 0xFFFF0000u) * dvv;
    }
  }
  const int e0 = offsets[v], e1 = offsets[v + 1];
  const int4* p = (const int4*)(meta + e0);  // e0 % 8 == 0 -> 64B aligned
  int rem = (e1 - e0) >> 3;                  // chunks of 8 edges
  int4 a0, a1, a2, a3;
  if (rem > 0) { a0 = p[0]; a1 = p[1]; a2 = p[2]; a3 = p[3]; }
  auto gather8 = [&](int4 c0, int4 c1, int4 c2, int4 c3) {
    int s[8] = {c0.x, c0.z, c1.x, c1.z, c2.x, c2.z, c3.x, c3.z};
    int wi[8] = {c0.y, c0.w, c1.y, c1.w, c2.y, c2.w, c3.y, c3.w};
    uint4 raw[8];
#pragma unroll
    for (int j = 0; j < 8; ++j) raw[j] = *(const uint4*)&H[(size_t)s[j] * 64 + (sl << 3)];
#pragma unroll
    for (int j = 0; j < 8; ++j) {
      const float wgt = __int_as_float(wi[j]);
      uint32_t u[4] = {raw[j].x, raw[j].y, raw[j].z, raw[j].w};
#pragma unroll
      for (int k = 0; k < 4; ++k) {
        acc[2 * k]     = fmaf(__uint_as_float(u[k] << 16), wgt, acc[2 * k]);
        acc[2 * k + 1] = fmaf(__uint_as_float(u[k] & 0xFFFF0000u), wgt, acc[2 * k + 1]);
      }
    }
  };
  while (rem > 1) {
    int4 b0 = p[4], b1 = p[5], b2 = p[6], b3 = p[7];
    gather8(a0, a1, a2, a3);
    a0 = b0; a1 = b1; a2 = b2; a3 = b3;
    p += 4;
    --rem;
  }
  if (rem == 1) gather8(a0, a1, a2, a3);
  const float4 blo = *(const float4*)&bias[sl << 3];
  const float4 bhi = *(const float4*)&bias[(sl << 3) + 4];
  float bb[8] = {blo.x, blo.y, blo.z, blo.w, bhi.x, bhi.y, bhi.z, bhi.w};
#pragma unroll
  for (int j = 0; j < 8; ++j) {
    acc[j] += bb[j];
    if (do_relu) acc[j] = fmaxf(acc[j], 0.f);
  }
  float* op = out + (size_t)v * 64 + (sl << 3);
  *(float4*)op = make_float4(acc[0], acc[1], acc[2], acc[3]);
  *(float4*)(op + 4) = make_float4(acc[4], acc[5], acc[6], acc[7]);
}

extern "C" void kernel_launch(void* const* d_in, const int* in_sizes, int n_in,
                              void* d_out, int out_size, void* d_ws, size_t ws_size,
                              hipStream_t stream) {
  const float* x = (const float*)d_in[0];
  const int* ei = (const int*)d_in[1];
  const float* W1 = (const float*)d_in[2];
  const float* b1 = (const float*)d_in[3];
  const float* W2 = (const float*)d_in[4];
  const float* b2 = (const float*)d_in[5];
  float* out = (float*)d_out;

  const int HID = in_sizes[3];           // 64
  const int IN_DIM = in_sizes[2] / HID;  // 512
  const int N = in_sizes[0] / IN_DIM;    // 50000
  const int E = in_sizes[1] / 2;         // 800000
  const int NB = (N + 255) / 256;        // 196 (<=256 for single-block scan)
  const size_t META_MAX = (size_t)E + 8 * (size_t)N;  // padded-CSR upper bound

  uint8_t* p = (uint8_t*)d_ws;
  auto alloc = [&](size_t bytes) {
    void* r = (void*)p;
    p += (bytes + 255) & ~(size_t)255;
    return r;
  };
  int* counts = (int*)alloc((size_t)N * 4);
  int* offsets = (int*)alloc((size_t)(N + 1) * 4);
  int* cursor = (int*)alloc((size_t)N * 4);
  int* bsum = (int*)alloc((size_t)NB * 4);
  int* boff = (int*)alloc((size_t)NB * 4);
  float* dinv = (float*)alloc((size_t)N * 4);
  int2* meta = (int2*)alloc(META_MAX * 8);
  ushort* hb = (ushort*)alloc((size_t)N * HID * 2);  // bf16 gemm out
  float* h = (float*)alloc((size_t)N * HID * 4);     // f32 agg1 out
  short8* wh1 = (short8*)alloc((size_t)(IN_DIM >> 5) * 256 * 16);
  short8* wl1 = (short8*)alloc((size_t)(IN_DIM >> 5) * 256 * 16);
  short8* wh2 = (short8*)alloc((size_t)(HID >> 5) * 256 * 16);
  short8* wl2 = (short8*)alloc((size_t)(HID >> 5) * 256 * 16);

  const int* srcp = ei;
  const int* dstp = ei + E;

  hipMemsetAsync(counts, 0, (size_t)N * 4, stream);
  hist_kernel<<<(E + 255) / 256, 256, 0, stream>>>(dstp, E, counts);
  bsum_kernel<<<NB, 256, 0, stream>>>(counts, bsum, N);
  scan_bsums_kernel<<<1, 256, 0, stream>>>(bsum, boff, NB);
  scan_apply_kernel<<<NB, 256, 0, stream>>>(counts, boff, offsets, cursor, dinv, meta, N);
  fill_kernel<<<(E + 255) / 256, 256, 0, stream>>>(srcp, dstp, E, cursor, dinv, meta);

  const int wtot = (IN_DIM >> 5) * 256 + (HID >> 5) * 256;
  wfrag_kernel<<<(wtot + 255) / 256, 256, 0, stream>>>(W1, W2, wh1, wl1, wh2, wl2,
                                                       IN_DIM, HID);

  gemm_mfma_kernel<<<(N + 127) / 128, 256, 0, stream>>>(x, wh1, wl1, hb, N, IN_DIM);
  agg_kernel<<<(N + 31) / 32, 256, 0, stream>>>(hb, offsets, meta, dinv, b1, h, N, 1);
  gemm_mfma_kernel<<<(N + 127) / 128, 256, 0, stream>>>(h, wh2, wl2, hb, N, HID);
  agg_kernel<<<(N + 31) / 32, 256, 0, stream>>>(hb, offsets, meta, dinv, b2, out, N, 0);
}